// Round 6
// baseline (2638.426 us; speedup 1.0000x reference)
//
#include <hip/hip_runtime.h>

// ---------------------------------------------------------------------------
// QGaloreLinear: y = x @ dequant(qw)^T + bias.  M=8192, N=4096, K=4096.
// R6: 256x256 tile, BK=32, 16x16x32 MFMA, 1 barrier/phase, 2 phases/kt.
//   LDS = 2 x 32 KiB = 64 KiB -> 2 blocks/CU (16 waves): cross-block wave
//   overlap hides barrier drain (the m97 mechanism R5 lacked at 1 block/CU).
//   Swizzle: 64B rows, 4x16B slots, slot_phys = slot ^ ((row>>1)&3)
//   (2 lanes/granule = free). Stages: p0:{A1(kt+1),B0(kt+2)} p1:{B1,A0(kt+2)};
//   vmcnt(3) at p1 retires all regions the next-kt reads touch (ledger-audited).
// ---------------------------------------------------------------------------

typedef __attribute__((ext_vector_type(8))) short bf16x8;
typedef __attribute__((ext_vector_type(8))) unsigned short ushort8;
typedef __attribute__((ext_vector_type(4))) float f32x4;

__device__ inline unsigned short f2bf(float f) {
  union { float f; unsigned int u; } v; v.f = f;
  unsigned int u = v.u;
  return (unsigned short)((u + 0x7fffu + ((u >> 16) & 1u)) >> 16);
}

// ---- kernel 1: dequantize int32 qweight -> bf16 Wb[N][K] --------------------
__global__ void dequant_w_kernel(const int* __restrict__ q,
                                 const float* __restrict__ sc,
                                 const float* __restrict__ zp,
                                 ushort8* __restrict__ wb, int total8) {
  int t = blockIdx.x * blockDim.x + threadIdx.x;
  if (t >= total8) return;
  const int4* q4 = (const int4*)q + (size_t)t * 2;
  int4 a = q4[0];
  int4 b = q4[1];
  int g = t >> 5;
  float s = sc[g], z = zp[g];
  ushort8 o;
  o[0] = f2bf(((float)a.x - z) * s);
  o[1] = f2bf(((float)a.y - z) * s);
  o[2] = f2bf(((float)a.z - z) * s);
  o[3] = f2bf(((float)a.w - z) * s);
  o[4] = f2bf(((float)b.x - z) * s);
  o[5] = f2bf(((float)b.y - z) * s);
  o[6] = f2bf(((float)b.z - z) * s);
  o[7] = f2bf(((float)b.w - z) * s);
  wb[t] = o;
}

// ---- kernel 2: convert fp32 x -> bf16 Xb[M][K] ------------------------------
__global__ void convert_x_kernel(const float* __restrict__ x,
                                 ushort8* __restrict__ xb, int total8) {
  int t = blockIdx.x * blockDim.x + threadIdx.x;
  if (t >= total8) return;
  const float4* x4 = (const float4*)x + (size_t)t * 2;
  float4 a = x4[0];
  float4 b = x4[1];
  ushort8 o;
  o[0] = f2bf(a.x); o[1] = f2bf(a.y); o[2] = f2bf(a.z); o[3] = f2bf(a.w);
  o[4] = f2bf(b.x); o[5] = f2bf(b.y); o[6] = f2bf(b.z); o[7] = f2bf(b.w);
  xb[t] = o;
}

// ---- kernel 3: 256x256, BK=32, 2 blocks/CU bf16 GEMM ------------------------
#define BM 256
#define BN 256
#define BK 32

#define BAR() asm volatile("s_barrier" ::: "memory")
#define MFMA16(d, x, y) d = __builtin_amdgcn_mfma_f32_16x16x32_bf16(x, y, d, 0, 0, 0)

__device__ inline void gload_lds16(const void* g, void* l) {
  __builtin_amdgcn_global_load_lds(
      (const __attribute__((address_space(1))) unsigned int*)g,
      (__attribute__((address_space(3))) unsigned int*)l, 16, 0, 0);
}

// Stage one 128-row x 32-col bf16 unit (8 KiB) with 512 threads: 1 gload each.
// LDS chunk p = wave*64+lane -> row = p>>2, slot_phys = p&3.
// Global source pre-swizzled: slot_logical = slot_phys ^ ((row>>1)&3).
__device__ inline void stage_unit32(const unsigned short* __restrict__ gsrc,
                                    char* lds_region, int K, int wave, int lane) {
  const int row  = wave * 16 + (lane >> 2);
  const int slot = (lane & 3) ^ ((row >> 1) & 3);
  gload_lds16(gsrc + (size_t)row * K + slot * 8,
              lds_region + (size_t)wave * 1024);
}

__global__ __launch_bounds__(512, 4)
void gemm256_kernel(const unsigned short* __restrict__ A,  // Xb, M x K
                    const unsigned short* __restrict__ B,  // Wb, N x K
                    const float* __restrict__ bias,
                    float* __restrict__ C,
                    int M, int N, int K) {
  extern __shared__ char lds[];   // buf: A@0(16K) B@16K(16K); dbuf @32K
  const int t    = threadIdx.x;
  const int lane = t & 63;
  const int wave = t >> 6;
  const int wm   = wave >> 2;          // 0..1 -> 128 rows
  const int wn   = wave & 3;           // 0..3 -> 64 cols
  const int lr   = lane & 15;
  const int hi   = lane >> 4;          // 0..3

  // T1: bijective XCD swizzle (nwg = 512, divisible by 8)
  const int nwg = gridDim.x;
  const int cpx = nwg >> 3;
  const int bid = blockIdx.x;
  const int swzb = (bid & 7) * cpx + (bid >> 3);
  const int ntn = N / BN;
  const int bm = swzb / ntn, bn = swzb % ntn;
  const int row0 = bm * BM, col0 = bn * BN;

  const int NT = K / BK;   // 128

  // lane-constant swizzled slot offset: row = 16*frag + lr -> ((row>>1)&3) = ((lr>>1)&3)
  const int soff = ((hi ^ ((lr >> 1) & 3))) * 16;

  const unsigned short* Asrc = A + (size_t)row0 * K;
  const unsigned short* Bsrc = B + (size_t)col0 * K;

  // regions within a 32 KiB buffer: A0@0 A1@8K B0@16K B1@24K
#define STAGE_A0(buf, kt) stage_unit32(Asrc + (size_t)(kt) * BK,           (buf),         K, wave, lane)
#define STAGE_A1(buf, kt) stage_unit32(Asrc + (size_t)128 * K + (kt) * BK, (buf) + 8192,  K, wave, lane)
#define STAGE_B0(buf, kt) stage_unit32(Bsrc + (size_t)(kt) * BK,           (buf) + 16384, K, wave, lane)
#define STAGE_B1(buf, kt) stage_unit32(Bsrc + (size_t)128 * K + (kt) * BK, (buf) + 24576, K, wave, lane)

  f32x4 acc[8][4] = {};
  bf16x8 aA[4];   // rows wm*128 +  0..63  of current kt (consumed p0)
  bf16x8 aB[4];   // rows wm*128 + 64..127 of current kt (consumed p1)
  bf16x8 b[4];    // all 4 n-frags of current kt (consumed p0+p1)

#define READ_A4(dst, mh, bufp) {                                              \
    const char* Ab_ = (const char*)(bufp) + ((size_t)((wm) * 128 + (mh) * 64 + lr)) * 64; \
    _Pragma("unroll")                                                         \
    for (int mm = 0; mm < 4; ++mm)                                            \
      dst[mm] = *(const bf16x8*)(Ab_ + mm * 1024 + soff);                     \
  }
#define READ_B4(bufp) {                                                       \
    const char* Bb_ = (const char*)(bufp) + 16384 + ((size_t)((wn) * 64 + lr)) * 64; \
    _Pragma("unroll")                                                         \
    for (int nn = 0; nn < 4; ++nn)                                            \
      b[nn] = *(const bf16x8*)(Bb_ + nn * 1024 + soff);                       \
  }
#define MFMA_PH(asrc, mh)                                                     \
    __builtin_amdgcn_s_setprio(1);                                            \
    _Pragma("unroll")                                                         \
    for (int mm = 0; mm < 4; ++mm)                                            \
      _Pragma("unroll")                                                       \
      for (int nn = 0; nn < 4; ++nn)                                          \
        MFMA16(acc[(mh) * 4 + mm][nn], asrc[mm], b[nn]);                      \
    __builtin_amdgcn_s_setprio(0);

  // ---- prologue: kt0 all 4 units; kt1 {A0,B0,B1} (A1(1) staged @p0(0)) ----
  char* buf0 = lds;
  char* buf1 = lds + 32768;
  STAGE_A0(buf0, 0); STAGE_A1(buf0, 0); STAGE_B0(buf0, 0); STAGE_B1(buf0, 0);
  STAGE_A0(buf1, 1); STAGE_B0(buf1, 1); STAGE_B1(buf1, 1);
  asm volatile("s_waitcnt vmcnt(3)" ::: "memory");   // retire kt0's 4 units
  BAR();
  READ_A4(aA, 0, buf0);
  READ_B4(buf0);

  for (int kt = 0; kt < NT; ++kt) {
    char* buf  = lds + ((kt & 1) << 15);
    char* nbuf = lds + (((kt & 1) ^ 1) << 15);

    // ===== p0: MFMA(aA, b) ; stage A1(kt+1)->nbuf, B0(kt+2)->buf ; read aB =====
    BAR();
    MFMA_PH(aA, 0);
    if (kt + 1 < NT) STAGE_A1(nbuf, kt + 1);
    if (kt + 2 < NT) STAGE_B0(buf, kt + 2);
    READ_A4(aB, 1, buf);

    // ===== p1: MFMA(aB, b) ; stage B1,A0(kt+2)->buf ; vmcnt ; read kt+1 =====
    BAR();
    MFMA_PH(aB, 1);
    if (kt + 2 < NT) {
      STAGE_B1(buf, kt + 2);
      STAGE_A0(buf, kt + 2);
      asm volatile("s_waitcnt vmcnt(3)" ::: "memory");
    } else if (kt + 1 < NT) {
      asm volatile("s_waitcnt vmcnt(0)" ::: "memory");
    }
    if (kt + 1 < NT) {
      READ_A4(aA, 0, nbuf);
      READ_B4(nbuf);
    }
  }

  // ---- epilogue: C = acc + bias ----
#pragma unroll
  for (int n = 0; n < 4; ++n) {
    const int col = col0 + wn * 64 + n * 16 + lr;
    const float bv = bias[col];
#pragma unroll
    for (int m = 0; m < 8; ++m) {
      const int rbase = row0 + wm * 128 + m * 16 + hi * 4;
#pragma unroll
      for (int j = 0; j < 4; ++j)
        C[(size_t)(rbase + j) * N + col] = acc[m][n][j] + bv;
    }
  }
#undef STAGE_A0
#undef STAGE_A1
#undef STAGE_B0
#undef STAGE_B1
#undef READ_A4
#undef READ_B4
#undef MFMA_PH
}

// ---------------------------------------------------------------------------
extern "C" void kernel_launch(void* const* d_in, const int* in_sizes, int n_in,
                              void* d_out, int out_size, void* d_ws, size_t ws_size,
                              hipStream_t stream) {
  const float* x      = (const float*)d_in[0];
  const int*   qw     = (const int*)d_in[1];
  const float* scales = (const float*)d_in[2];
  const float* zeros  = (const float*)d_in[3];
  const float* bias   = (const float*)d_in[4];
  float* out = (float*)d_out;

  const int OUT = in_sizes[4];                 // 4096
  const int IN  = in_sizes[1] / OUT;           // 4096
  const int M   = in_sizes[0] / IN;            // 8192

  unsigned short* wb = (unsigned short*)d_ws;                 // OUT*IN bf16
  unsigned short* xb = wb + (size_t)OUT * IN;                 // M*IN  bf16

  {
    int total8 = OUT * IN / 8;
    dequant_w_kernel<<<(total8 + 255) / 256, 256, 0, stream>>>(
        qw, scales, zeros, (ushort8*)wb, total8);
  }
  {
    int total8 = (int)((size_t)M * IN / 8);
    convert_x_kernel<<<(total8 + 255) / 256, 256, 0, stream>>>(
        x, (ushort8*)xb, total8);
  }
  {
    hipFuncSetAttribute((const void*)gemm256_kernel,
                        hipFuncAttributeMaxDynamicSharedMemorySize, 65536);
    dim3 grid((M / BM) * (OUT / BN));
    gemm256_kernel<<<grid, 512, 65536, stream>>>(xb, wb, bias, out, M, OUT, IN);
  }
}

// Round 7
// 271.151 us; speedup vs baseline: 9.7305x; 9.7305x over previous
//
#include <hip/hip_runtime.h>

// ---------------------------------------------------------------------------
// QGaloreLinear: y = x @ dequant(qw)^T + bias.  M=8192, N=4096, K=4096.
// R7: revert to R4 (best measured: 235.6us GEMM) + 2-kt unrolled, branchless
//   main loop (compile-time buffer alternation; guards only in 2-kt tail).
//   256x256 tile, BK=64, 16x16x32 MFMA, 1 barrier/phase, counted vmcnt(4).
//   NOTE: __launch_bounds__(512,2) is load-bearing — (512,4) caps VGPR at 128
//   and spills the 128-reg accumulator to scratch (R6: 13GB scratch traffic).
// ---------------------------------------------------------------------------

typedef __attribute__((ext_vector_type(8))) short bf16x8;
typedef __attribute__((ext_vector_type(8))) unsigned short ushort8;
typedef __attribute__((ext_vector_type(4))) float f32x4;

__device__ inline unsigned short f2bf(float f) {
  union { float f; unsigned int u; } v; v.f = f;
  unsigned int u = v.u;
  return (unsigned short)((u + 0x7fffu + ((u >> 16) & 1u)) >> 16);
}

// ---- kernel 1: dequantize int32 qweight -> bf16 Wb[N][K] --------------------
__global__ void dequant_w_kernel(const int* __restrict__ q,
                                 const float* __restrict__ sc,
                                 const float* __restrict__ zp,
                                 ushort8* __restrict__ wb, int total8) {
  int t = blockIdx.x * blockDim.x + threadIdx.x;
  if (t >= total8) return;
  const int4* q4 = (const int4*)q + (size_t)t * 2;
  int4 a = q4[0];
  int4 b = q4[1];
  int g = t >> 5;
  float s = sc[g], z = zp[g];
  ushort8 o;
  o[0] = f2bf(((float)a.x - z) * s);
  o[1] = f2bf(((float)a.y - z) * s);
  o[2] = f2bf(((float)a.z - z) * s);
  o[3] = f2bf(((float)a.w - z) * s);
  o[4] = f2bf(((float)b.x - z) * s);
  o[5] = f2bf(((float)b.y - z) * s);
  o[6] = f2bf(((float)b.z - z) * s);
  o[7] = f2bf(((float)b.w - z) * s);
  wb[t] = o;
}

// ---- kernel 2: convert fp32 x -> bf16 Xb[M][K] ------------------------------
__global__ void convert_x_kernel(const float* __restrict__ x,
                                 ushort8* __restrict__ xb, int total8) {
  int t = blockIdx.x * blockDim.x + threadIdx.x;
  if (t >= total8) return;
  const float4* x4 = (const float4*)x + (size_t)t * 2;
  float4 a = x4[0];
  float4 b = x4[1];
  ushort8 o;
  o[0] = f2bf(a.x); o[1] = f2bf(a.y); o[2] = f2bf(a.z); o[3] = f2bf(a.w);
  o[4] = f2bf(b.x); o[5] = f2bf(b.y); o[6] = f2bf(b.z); o[7] = f2bf(b.w);
  xb[t] = o;
}

// ---- kernel 3: 256x256 single-barrier-phase bf16 GEMM -----------------------
#define BM 256
#define BN 256
#define BK 64

#define BAR() asm volatile("s_barrier" ::: "memory")
#define MFMA16(d, x, y) d = __builtin_amdgcn_mfma_f32_16x16x32_bf16(x, y, d, 0, 0, 0)

__device__ inline void gload_lds16(const void* g, void* l) {
  __builtin_amdgcn_global_load_lds(
      (const __attribute__((address_space(1))) unsigned int*)g,
      (__attribute__((address_space(3))) unsigned int*)l, 16, 0, 0);
}

// Stage one 128-row x 64-col bf16 half-tile (16 KiB). Global 16B-slot is
// pre-swizzled (slot ^ (row&7)); LDS dest linear (rule #21 both-sides).
__device__ inline void stage_half(const unsigned short* __restrict__ gsrc,
                                  char* lds_region, int K, int wave, int lane) {
  const int l3  = lane >> 3;
  const int swz = ((lane & 7) ^ l3) * 8;
#pragma unroll
  for (int inst = 0; inst < 2; ++inst) {
    const int row = inst * 64 + wave * 8 + l3;
    gload_lds16(gsrc + (size_t)row * K + swz,
                lds_region + (size_t)(inst * 512 + wave * 64) * 16);
  }
}

__global__ __launch_bounds__(512, 2)
void gemm256_kernel(const unsigned short* __restrict__ A,  // Xb, M x K
                    const unsigned short* __restrict__ B,  // Wb, N x K
                    const float* __restrict__ bias,
                    float* __restrict__ C,
                    int M, int N, int K) {
  extern __shared__ char lds[];   // buf: A0@0 A1@16K B0@32K B1@48K; dbuf @64K
  const int t    = threadIdx.x;
  const int lane = t & 63;
  const int wave = t >> 6;
  const int wm   = wave >> 2;
  const int wn   = wave & 3;
  const int lr   = lane & 15;
  const int hi   = lane >> 4;
  const int l7   = lane & 7;

  // T1: bijective XCD swizzle (nwg % 8 == 0)
  const int nwg = gridDim.x;
  const int cpx = nwg >> 3;
  const int bid = blockIdx.x;
  const int swzb = (bid & 7) * cpx + (bid >> 3);
  const int ntn = N / BN;
  const int bm = swzb / ntn, bn = swzb % ntn;
  const int row0 = bm * BM, col0 = bn * BN;

  const int NT = K / BK;   // 64

  const int soff0 = ((hi) ^ l7) * 16;
  const int soff1 = ((4 + hi) ^ l7) * 16;

  const unsigned short* Asrc = A + (size_t)row0 * K;
  const unsigned short* Bsrc = B + (size_t)col0 * K;

#define STAGE_A0(buf, kt) stage_half(Asrc + (size_t)(kt) * BK,           (buf),         K, wave, lane)
#define STAGE_A1(buf, kt) stage_half(Asrc + (size_t)128 * K + (kt) * BK, (buf) + 16384, K, wave, lane)
#define STAGE_B0(buf, kt) stage_half(Bsrc + (size_t)(kt) * BK,           (buf) + 32768, K, wave, lane)
#define STAGE_B1(buf, kt) stage_half(Bsrc + (size_t)128 * K + (kt) * BK, (buf) + 49152, K, wave, lane)

  f32x4 acc[8][4] = {};
  bf16x8 a[4][2];   // current m-half, 4 frags x 2 ks
  bf16x8 b[4][2];   // all 4 n-frags of this kt

#define READ_A(mh, bufp) {                                                    \
    const char* Ab_ = (const char*)(bufp) + wm * 16384 + (mh) * 8192;         \
    _Pragma("unroll")                                                         \
    for (int mm = 0; mm < 4; ++mm) {                                          \
      const int r_ = (mm * 16 + lr) * 128;                                    \
      a[mm][0] = *(const bf16x8*)(Ab_ + r_ + soff0);                          \
      a[mm][1] = *(const bf16x8*)(Ab_ + r_ + soff1);                          \
    } }
#define READ_B(nh, bufp) {                                                    \
    const char* Bb_ = (const char*)(bufp) + 32768 + wn * 8192;                \
    _Pragma("unroll")                                                         \
    for (int nn = 0; nn < 2; ++nn) {                                          \
      const int r_ = (((nh) * 2 + nn) * 16 + lr) * 128;                       \
      b[(nh) * 2 + nn][0] = *(const bf16x8*)(Bb_ + r_ + soff0);               \
      b[(nh) * 2 + nn][1] = *(const bf16x8*)(Bb_ + r_ + soff1);               \
    } }
#define MFMA_QUAD(mh, nh)                                                     \
    __builtin_amdgcn_s_setprio(1);                                            \
    _Pragma("unroll")                                                         \
    for (int mm = 0; mm < 4; ++mm)                                            \
      _Pragma("unroll")                                                       \
      for (int nn = 0; nn < 2; ++nn) {                                        \
        MFMA16(acc[(mh) * 4 + mm][(nh) * 2 + nn], a[mm][0], b[(nh) * 2 + nn][0]); \
        MFMA16(acc[(mh) * 4 + mm][(nh) * 2 + nn], a[mm][1], b[(nh) * 2 + nn][1]); \
      }                                                                       \
    __builtin_amdgcn_s_setprio(0);

  // One K-tile body. buf/nbuf are compile-time-known pointers in the unrolled
  // main loop. GUARDED=0 removes all tail checks (valid while kt < NT-2).
#define KT_BODY(buf, nbuf, kt, GUARDED)                                       \
  {                                                                           \
    /* q0: MFMA(m0,n01) ; stage A1(kt+1)->nbuf ; read b23 */                  \
    BAR();                                                                    \
    MFMA_QUAD(0, 0);                                                          \
    if (!(GUARDED) || (kt) + 1 < NT) STAGE_A1(nbuf, (kt) + 1);                \
    READ_B(1, buf);                                                           \
    /* q1: MFMA(m0,n23) ; stage B0(kt+2)->buf ; read a(m1) */                 \
    BAR();                                                                    \
    MFMA_QUAD(0, 1);                                                          \
    if (!(GUARDED) || (kt) + 2 < NT) STAGE_B0(buf, (kt) + 2);                 \
    READ_A(1, buf);                                                           \
    /* q2: MFMA(m1,n01) ; stage B1(kt+2)->buf ; vmcnt */                      \
    BAR();                                                                    \
    MFMA_QUAD(1, 0);                                                          \
    if (!(GUARDED) || (kt) + 2 < NT) {                                        \
      STAGE_B1(buf, (kt) + 2);                                                \
      asm volatile("s_waitcnt vmcnt(4)" ::: "memory");                        \
    } else {                                                                  \
      asm volatile("s_waitcnt vmcnt(0)" ::: "memory");                        \
    }                                                                         \
    /* q3: MFMA(m1,n23) ; stage A0(kt+2)->buf ; read next-kt a(m0),b(n0) */   \
    BAR();                                                                    \
    MFMA_QUAD(1, 1);                                                          \
    if (!(GUARDED) || (kt) + 2 < NT) STAGE_A0(buf, (kt) + 2);                 \
    if (!(GUARDED) || (kt) + 1 < NT) {                                        \
      READ_A(0, nbuf);                                                        \
      READ_B(0, nbuf);                                                        \
    }                                                                         \
  }

  // ---- prologue: stage buf0 fully + buf1 {A0,B0,B1}; A1(1) comes @q0(0) ----
  char* buf0 = lds;
  char* buf1 = lds + 65536;
  STAGE_A0(buf0, 0); STAGE_A1(buf0, 0); STAGE_B0(buf0, 0); STAGE_B1(buf0, 0);
  STAGE_A0(buf1, 1); STAGE_B0(buf1, 1); STAGE_B1(buf1, 1);
  asm volatile("s_waitcnt vmcnt(6)" ::: "memory");
  BAR();
  READ_A(0, buf0);
  READ_B(0, buf0);

  // ---- main: branchless pairs while kt+1 < NT-2  (kt = 0 .. NT-4) ----
  int kt = 0;
  for (; kt + 3 < NT; kt += 2) {
    KT_BODY(buf0, buf1, kt, 0);
    KT_BODY(buf1, buf0, kt + 1, 0);
  }
  // ---- tail: last 2 K-tiles, guarded ----
  for (; kt < NT; ++kt) {
    char* buf  = lds + ((kt & 1) << 16);
    char* nbuf = lds + (((kt & 1) ^ 1) << 16);
    KT_BODY(buf, nbuf, kt, 1);
  }

  // ---- epilogue: C = acc + bias ----
#pragma unroll
  for (int n = 0; n < 4; ++n) {
    const int col = col0 + wn * 64 + n * 16 + lr;
    const float bv = bias[col];
#pragma unroll
    for (int m = 0; m < 8; ++m) {
      const int rbase = row0 + wm * 128 + m * 16 + hi * 4;
#pragma unroll
      for (int j = 0; j < 4; ++j)
        C[(size_t)(rbase + j) * N + col] = acc[m][n][j] + bv;
    }
  }
#undef STAGE_A0
#undef STAGE_A1
#undef STAGE_B0
#undef STAGE_B1
#undef READ_A
#undef READ_B
#undef MFMA_QUAD
#undef KT_BODY
}

// ---------------------------------------------------------------------------
extern "C" void kernel_launch(void* const* d_in, const int* in_sizes, int n_in,
                              void* d_out, int out_size, void* d_ws, size_t ws_size,
                              hipStream_t stream) {
  const float* x      = (const float*)d_in[0];
  const int*   qw     = (const int*)d_in[1];
  const float* scales = (const float*)d_in[2];
  const float* zeros  = (const float*)d_in[3];
  const float* bias   = (const float*)d_in[4];
  float* out = (float*)d_out;

  const int OUT = in_sizes[4];                 // 4096
  const int IN  = in_sizes[1] / OUT;           // 4096
  const int M   = in_sizes[0] / IN;            // 8192

  unsigned short* wb = (unsigned short*)d_ws;                 // OUT*IN bf16
  unsigned short* xb = wb + (size_t)OUT * IN;                 // M*IN  bf16

  {
    int total8 = OUT * IN / 8;
    dequant_w_kernel<<<(total8 + 255) / 256, 256, 0, stream>>>(
        qw, scales, zeros, (ushort8*)wb, total8);
  }
  {
    int total8 = (int)((size_t)M * IN / 8);
    convert_x_kernel<<<(total8 + 255) / 256, 256, 0, stream>>>(
        x, (ushort8*)xb, total8);
  }
  {
    hipFuncSetAttribute((const void*)gemm256_kernel,
                        hipFuncAttributeMaxDynamicSharedMemorySize, 131072);
    dim3 grid((M / BM) * (OUT / BN));
    gemm256_kernel<<<grid, 512, 131072, stream>>>(xb, wb, bias, out, M, OUT, IN);
  }
}

// Round 9
// 268.720 us; speedup vs baseline: 9.8185x; 1.0090x over previous
//
#include <hip/hip_runtime.h>

// ---------------------------------------------------------------------------
// QGaloreLinear: y = x @ dequant(qw)^T + bias.  M=8192, N=4096, K=4096.
// R9: GEMM reverted to R7-exact (proven: 218us, MfmaUtil 56.7%, 0 conflicts).
//   R8's 2-phase/kt variant RACED: it cut two LDS overwrite-after-read
//   distances to 1 barrier (ds_read queue can back up past the ~500cy HBM
//   latency cushion) -> absmax 44. The 2-barrier separation is load-bearing.
//   Kept from R8: fused one-launch prep (dequant W + convert x), orthogonal.
//   NOTE: __launch_bounds__(512,2) is load-bearing (R6: (512,4) spilled).
// ---------------------------------------------------------------------------

typedef __attribute__((ext_vector_type(8))) short bf16x8;
typedef __attribute__((ext_vector_type(8))) unsigned short ushort8;
typedef __attribute__((ext_vector_type(4))) float f32x4;

__device__ inline unsigned short f2bf(float f) {
  union { float f; unsigned int u; } v; v.f = f;
  unsigned int u = v.u;
  return (unsigned short)((u + 0x7fffu + ((u >> 16) & 1u)) >> 16);
}

// ---- kernel 1: fused  dequant(W)->bf16  +  convert(x)->bf16 -----------------
__global__ void prep_kernel(const int* __restrict__ q,
                            const float* __restrict__ sc,
                            const float* __restrict__ zp,
                            ushort8* __restrict__ wb,
                            const float* __restrict__ x,
                            ushort8* __restrict__ xb,
                            int nw8, int nx8) {
  int t = blockIdx.x * blockDim.x + threadIdx.x;
  if (t < nw8) {
    const int4* q4 = (const int4*)q + (size_t)t * 2;
    int4 a = q4[0];
    int4 b = q4[1];
    int g = t >> 5;
    float s = sc[g], z = zp[g];
    ushort8 o;
    o[0] = f2bf(((float)a.x - z) * s);
    o[1] = f2bf(((float)a.y - z) * s);
    o[2] = f2bf(((float)a.z - z) * s);
    o[3] = f2bf(((float)a.w - z) * s);
    o[4] = f2bf(((float)b.x - z) * s);
    o[5] = f2bf(((float)b.y - z) * s);
    o[6] = f2bf(((float)b.z - z) * s);
    o[7] = f2bf(((float)b.w - z) * s);
    wb[t] = o;
  } else {
    int u = t - nw8;
    if (u >= nx8) return;
    const float4* x4 = (const float4*)x + (size_t)u * 2;
    float4 a = x4[0];
    float4 b = x4[1];
    ushort8 o;
    o[0] = f2bf(a.x); o[1] = f2bf(a.y); o[2] = f2bf(a.z); o[3] = f2bf(a.w);
    o[4] = f2bf(b.x); o[5] = f2bf(b.y); o[6] = f2bf(b.z); o[7] = f2bf(b.w);
    xb[u] = o;
  }
}

// ---- kernel 2: 256x256 single-barrier-phase bf16 GEMM (R7-exact) ------------
#define BM 256
#define BN 256
#define BK 64

#define BAR() asm volatile("s_barrier" ::: "memory")
#define MFMA16(d, x, y) d = __builtin_amdgcn_mfma_f32_16x16x32_bf16(x, y, d, 0, 0, 0)

__device__ inline void gload_lds16(const void* g, void* l) {
  __builtin_amdgcn_global_load_lds(
      (const __attribute__((address_space(1))) unsigned int*)g,
      (__attribute__((address_space(3))) unsigned int*)l, 16, 0, 0);
}

// Stage one 128-row x 64-col bf16 half-tile (16 KiB). Global 16B-slot is
// pre-swizzled (slot ^ (row&7)); LDS dest linear (rule #21 both-sides).
__device__ inline void stage_half(const unsigned short* __restrict__ gsrc,
                                  char* lds_region, int K, int wave, int lane) {
  const int l3  = lane >> 3;
  const int swz = ((lane & 7) ^ l3) * 8;
#pragma unroll
  for (int inst = 0; inst < 2; ++inst) {
    const int row = inst * 64 + wave * 8 + l3;
    gload_lds16(gsrc + (size_t)row * K + swz,
                lds_region + (size_t)(inst * 512 + wave * 64) * 16);
  }
}

__global__ __launch_bounds__(512, 2)
void gemm256_kernel(const unsigned short* __restrict__ A,  // Xb, M x K
                    const unsigned short* __restrict__ B,  // Wb, N x K
                    const float* __restrict__ bias,
                    float* __restrict__ C,
                    int M, int N, int K) {
  extern __shared__ char lds[];   // buf: A0@0 A1@16K B0@32K B1@48K; dbuf @64K
  const int t    = threadIdx.x;
  const int lane = t & 63;
  const int wave = t >> 6;
  const int wm   = wave >> 2;
  const int wn   = wave & 3;
  const int lr   = lane & 15;
  const int hi   = lane >> 4;
  const int l7   = lane & 7;

  // T1: bijective XCD swizzle (nwg % 8 == 0)
  const int nwg = gridDim.x;
  const int cpx = nwg >> 3;
  const int bid = blockIdx.x;
  const int swzb = (bid & 7) * cpx + (bid >> 3);
  const int ntn = N / BN;
  const int bm = swzb / ntn, bn = swzb % ntn;
  const int row0 = bm * BM, col0 = bn * BN;

  const int NT = K / BK;   // 64

  const int soff0 = ((hi) ^ l7) * 16;
  const int soff1 = ((4 + hi) ^ l7) * 16;

  const unsigned short* Asrc = A + (size_t)row0 * K;
  const unsigned short* Bsrc = B + (size_t)col0 * K;

#define STAGE_A0(buf, kt) stage_half(Asrc + (size_t)(kt) * BK,           (buf),         K, wave, lane)
#define STAGE_A1(buf, kt) stage_half(Asrc + (size_t)128 * K + (kt) * BK, (buf) + 16384, K, wave, lane)
#define STAGE_B0(buf, kt) stage_half(Bsrc + (size_t)(kt) * BK,           (buf) + 32768, K, wave, lane)
#define STAGE_B1(buf, kt) stage_half(Bsrc + (size_t)128 * K + (kt) * BK, (buf) + 49152, K, wave, lane)

  f32x4 acc[8][4] = {};
  bf16x8 a[4][2];   // current m-half, 4 frags x 2 ks
  bf16x8 b[4][2];   // all 4 n-frags of this kt

#define READ_A(mh, bufp) {                                                    \
    const char* Ab_ = (const char*)(bufp) + wm * 16384 + (mh) * 8192;         \
    _Pragma("unroll")                                                         \
    for (int mm = 0; mm < 4; ++mm) {                                          \
      const int r_ = (mm * 16 + lr) * 128;                                    \
      a[mm][0] = *(const bf16x8*)(Ab_ + r_ + soff0);                          \
      a[mm][1] = *(const bf16x8*)(Ab_ + r_ + soff1);                          \
    } }
#define READ_B(nh, bufp) {                                                    \
    const char* Bb_ = (const char*)(bufp) + 32768 + wn * 8192;                \
    _Pragma("unroll")                                                         \
    for (int nn = 0; nn < 2; ++nn) {                                          \
      const int r_ = (((nh) * 2 + nn) * 16 + lr) * 128;                       \
      b[(nh) * 2 + nn][0] = *(const bf16x8*)(Bb_ + r_ + soff0);               \
      b[(nh) * 2 + nn][1] = *(const bf16x8*)(Bb_ + r_ + soff1);               \
    } }
#define MFMA_QUAD(mh, nh)                                                     \
    __builtin_amdgcn_s_setprio(1);                                            \
    _Pragma("unroll")                                                         \
    for (int mm = 0; mm < 4; ++mm)                                            \
      _Pragma("unroll")                                                       \
      for (int nn = 0; nn < 2; ++nn) {                                        \
        MFMA16(acc[(mh) * 4 + mm][(nh) * 2 + nn], a[mm][0], b[(nh) * 2 + nn][0]); \
        MFMA16(acc[(mh) * 4 + mm][(nh) * 2 + nn], a[mm][1], b[(nh) * 2 + nn][1]); \
      }                                                                       \
    __builtin_amdgcn_s_setprio(0);

  // One K-tile body (R7-exact). All overwrite-after-read distances >= 2
  // barriers; q2's vmcnt(4) retires exactly through A1(kt+1).
#define KT_BODY(buf, nbuf, kt, GUARDED)                                       \
  {                                                                           \
    /* q0: MFMA(m0,n01) ; stage A1(kt+1)->nbuf ; read b23 */                  \
    BAR();                                                                    \
    MFMA_QUAD(0, 0);                                                          \
    if (!(GUARDED) || (kt) + 1 < NT) STAGE_A1(nbuf, (kt) + 1);                \
    READ_B(1, buf);                                                           \
    /* q1: MFMA(m0,n23) ; stage B0(kt+2)->buf ; read a(m1) */                 \
    BAR();                                                                    \
    MFMA_QUAD(0, 1);                                                          \
    if (!(GUARDED) || (kt) + 2 < NT) STAGE_B0(buf, (kt) + 2);                 \
    READ_A(1, buf);                                                           \
    /* q2: MFMA(m1,n01) ; stage B1(kt+2)->buf ; vmcnt */                      \
    BAR();                                                                    \
    MFMA_QUAD(1, 0);                                                          \
    if (!(GUARDED) || (kt) + 2 < NT) {                                        \
      STAGE_B1(buf, (kt) + 2);                                                \
      asm volatile("s_waitcnt vmcnt(4)" ::: "memory");                        \
    } else {                                                                  \
      asm volatile("s_waitcnt vmcnt(0)" ::: "memory");                        \
    }                                                                         \
    /* q3: MFMA(m1,n23) ; stage A0(kt+2)->buf ; read next-kt a(m0),b(n0) */   \
    BAR();                                                                    \
    MFMA_QUAD(1, 1);                                                          \
    if (!(GUARDED) || (kt) + 2 < NT) STAGE_A0(buf, (kt) + 2);                 \
    if (!(GUARDED) || (kt) + 1 < NT) {                                        \
      READ_A(0, nbuf);                                                        \
      READ_B(0, nbuf);                                                        \
    }                                                                         \
  }

  // ---- prologue: stage buf0 fully + buf1 {A0,B0,B1}; A1(1) comes @q0(0) ----
  char* buf0 = lds;
  char* buf1 = lds + 65536;
  STAGE_A0(buf0, 0); STAGE_A1(buf0, 0); STAGE_B0(buf0, 0); STAGE_B1(buf0, 0);
  STAGE_A0(buf1, 1); STAGE_B0(buf1, 1); STAGE_B1(buf1, 1);
  asm volatile("s_waitcnt vmcnt(6)" ::: "memory");
  BAR();
  READ_A(0, buf0);
  READ_B(0, buf0);

  // ---- main: branchless pairs (kt = 0 .. NT-4) ----
  int kt = 0;
  for (; kt + 3 < NT; kt += 2) {
    KT_BODY(buf0, buf1, kt, 0);
    KT_BODY(buf1, buf0, kt + 1, 0);
  }
  // ---- tail: last 2 K-tiles, guarded ----
  for (; kt < NT; ++kt) {
    char* buf  = lds + ((kt & 1) << 16);
    char* nbuf = lds + (((kt & 1) ^ 1) << 16);
    KT_BODY(buf, nbuf, kt, 1);
  }

  // ---- epilogue: C = acc + bias ----
#pragma unroll
  for (int n = 0; n < 4; ++n) {
    const int col = col0 + wn * 64 + n * 16 + lr;
    const float bv = bias[col];
#pragma unroll
    for (int m = 0; m < 8; ++m) {
      const int rbase = row0 + wm * 128 + m * 16 + hi * 4;
#pragma unroll
      for (int j = 0; j < 4; ++j)
        C[(size_t)(rbase + j) * N + col] = acc[m][n][j] + bv;
    }
  }
#undef STAGE_A0
#undef STAGE_A1
#undef STAGE_B0
#undef STAGE_B1
#undef READ_A
#undef READ_B
#undef MFMA_QUAD
#undef KT_BODY
}

// ---------------------------------------------------------------------------
extern "C" void kernel_launch(void* const* d_in, const int* in_sizes, int n_in,
                              void* d_out, int out_size, void* d_ws, size_t ws_size,
                              hipStream_t stream) {
  const float* x      = (const float*)d_in[0];
  const int*   qw     = (const int*)d_in[1];
  const float* scales = (const float*)d_in[2];
  const float* zeros  = (const float*)d_in[3];
  const float* bias   = (const float*)d_in[4];
  float* out = (float*)d_out;

  const int OUT = in_sizes[4];                 // 4096
  const int IN  = in_sizes[1] / OUT;           // 4096
  const int M   = in_sizes[0] / IN;            // 8192

  unsigned short* wb = (unsigned short*)d_ws;                 // OUT*IN bf16
  unsigned short* xb = wb + (size_t)OUT * IN;                 // M*IN  bf16

  {
    int nw8 = OUT * IN / 8;                    // multiple of 256 -> no straddle
    int nx8 = (int)((size_t)M * IN / 8);
    int total = nw8 + nx8;
    prep_kernel<<<(total + 255) / 256, 256, 0, stream>>>(
        qw, scales, zeros, (ushort8*)wb, x, (ushort8*)xb, nw8, nx8);
  }
  {
    hipFuncSetAttribute((const void*)gemm256_kernel,
                        hipFuncAttributeMaxDynamicSharedMemorySize, 131072);
    dim3 grid((M / BM) * (OUT / BN));
    gemm256_kernel<<<grid, 512, 131072, stream>>>(xb, wb, bias, out, M, OUT, IN);
  }
}

// Round 11
// 263.646 us; speedup vs baseline: 10.0074x; 1.0192x over previous
//
#include <hip/hip_runtime.h>

// ---------------------------------------------------------------------------
// QGaloreLinear: y = x @ dequant(qw)^T + bias.  M=8192, N=4096, K=4096.
// R11: R9's proven main loop (R7 schedule) + coalesced LDS-transpose epilogue.
//   R10 root cause (recorded): vmcnt is PER-WAVE; reading an LDS region staged
//   cooperatively by all waves is only safe after a barrier that FOLLOWS every
//   wave's vmcnt. R7's q3-only nbuf reads satisfy this; R5/R10's q2 reads
//   (same segment as own vmcnt) raced. The {4,8,0,12} read split is forced.
//   Epilogue: per-wave 16KB LDS transpose (272B padded rows), float4 stores
//   -> full 128B lines (WRITE_SIZE 162->~132MB), 32 stores vs 128.
//   NOTE: __launch_bounds__(512,2) is load-bearing (R6: (512,4) spilled).
// ---------------------------------------------------------------------------

typedef __attribute__((ext_vector_type(8))) short bf16x8;
typedef __attribute__((ext_vector_type(8))) unsigned short ushort8;
typedef __attribute__((ext_vector_type(4))) float f32x4;

__device__ inline unsigned short f2bf(float f) {
  union { float f; unsigned int u; } v; v.f = f;
  unsigned int u = v.u;
  return (unsigned short)((u + 0x7fffu + ((u >> 16) & 1u)) >> 16);
}

// ---- kernel 1: fused  dequant(W)->bf16  +  convert(x)->bf16 -----------------
__global__ void prep_kernel(const int* __restrict__ q,
                            const float* __restrict__ sc,
                            const float* __restrict__ zp,
                            ushort8* __restrict__ wb,
                            const float* __restrict__ x,
                            ushort8* __restrict__ xb,
                            int nw8, int nx8) {
  int t = blockIdx.x * blockDim.x + threadIdx.x;
  if (t < nw8) {
    const int4* q4 = (const int4*)q + (size_t)t * 2;
    int4 a = q4[0];
    int4 b = q4[1];
    int g = t >> 5;
    float s = sc[g], z = zp[g];
    ushort8 o;
    o[0] = f2bf(((float)a.x - z) * s);
    o[1] = f2bf(((float)a.y - z) * s);
    o[2] = f2bf(((float)a.z - z) * s);
    o[3] = f2bf(((float)a.w - z) * s);
    o[4] = f2bf(((float)b.x - z) * s);
    o[5] = f2bf(((float)b.y - z) * s);
    o[6] = f2bf(((float)b.z - z) * s);
    o[7] = f2bf(((float)b.w - z) * s);
    wb[t] = o;
  } else {
    int u = t - nw8;
    if (u >= nx8) return;
    const float4* x4 = (const float4*)x + (size_t)u * 2;
    float4 a = x4[0];
    float4 b = x4[1];
    ushort8 o;
    o[0] = f2bf(a.x); o[1] = f2bf(a.y); o[2] = f2bf(a.z); o[3] = f2bf(a.w);
    o[4] = f2bf(b.x); o[5] = f2bf(b.y); o[6] = f2bf(b.z); o[7] = f2bf(b.w);
    xb[u] = o;
  }
}

// ---- kernel 2: 256x256 single-barrier-phase bf16 GEMM -----------------------
#define BM 256
#define BN 256
#define BK 64

#define BAR() asm volatile("s_barrier" ::: "memory")
#define MFMA16(d, x, y) d = __builtin_amdgcn_mfma_f32_16x16x32_bf16(x, y, d, 0, 0, 0)

__device__ inline void gload_lds16(const void* g, void* l) {
  __builtin_amdgcn_global_load_lds(
      (const __attribute__((address_space(1))) unsigned int*)g,
      (__attribute__((address_space(3))) unsigned int*)l, 16, 0, 0);
}

// Stage one 128-row x 64-col bf16 half-tile (16 KiB). Global 16B-slot is
// pre-swizzled (slot ^ (row&7)); LDS dest linear (rule #21 both-sides).
__device__ inline void stage_half(const unsigned short* __restrict__ gsrc,
                                  char* lds_region, int K, int wave, int lane) {
  const int l3  = lane >> 3;
  const int swz = ((lane & 7) ^ l3) * 8;
#pragma unroll
  for (int inst = 0; inst < 2; ++inst) {
    const int row = inst * 64 + wave * 8 + l3;
    gload_lds16(gsrc + (size_t)row * K + swz,
                lds_region + (size_t)(inst * 512 + wave * 64) * 16);
  }
}

__global__ __launch_bounds__(512, 2)
void gemm256_kernel(const unsigned short* __restrict__ A,  // Xb, M x K
                    const unsigned short* __restrict__ B,  // Wb, N x K
                    const float* __restrict__ bias,
                    float* __restrict__ C,
                    int M, int N, int K) {
  extern __shared__ char lds[];   // buf: A0@0 A1@16K B0@32K B1@48K; dbuf @64K
  const int t    = threadIdx.x;
  const int lane = t & 63;
  const int wave = t >> 6;
  const int wm   = wave >> 2;
  const int wn   = wave & 3;
  const int lr   = lane & 15;
  const int hi   = lane >> 4;
  const int l7   = lane & 7;

  // T1: bijective XCD swizzle (nwg % 8 == 0)
  const int nwg = gridDim.x;
  const int cpx = nwg >> 3;
  const int bid = blockIdx.x;
  const int swzb = (bid & 7) * cpx + (bid >> 3);
  const int ntn = N / BN;
  const int bm = swzb / ntn, bn = swzb % ntn;
  const int row0 = bm * BM, col0 = bn * BN;

  const int NT = K / BK;   // 64

  const int soff0 = ((hi) ^ l7) * 16;
  const int soff1 = ((4 + hi) ^ l7) * 16;

  const unsigned short* Asrc = A + (size_t)row0 * K;
  const unsigned short* Bsrc = B + (size_t)col0 * K;

#define STAGE_A0(buf, kt) stage_half(Asrc + (size_t)(kt) * BK,           (buf),         K, wave, lane)
#define STAGE_A1(buf, kt) stage_half(Asrc + (size_t)128 * K + (kt) * BK, (buf) + 16384, K, wave, lane)
#define STAGE_B0(buf, kt) stage_half(Bsrc + (size_t)(kt) * BK,           (buf) + 32768, K, wave, lane)
#define STAGE_B1(buf, kt) stage_half(Bsrc + (size_t)128 * K + (kt) * BK, (buf) + 49152, K, wave, lane)

  f32x4 acc[8][4] = {};
  bf16x8 a[4][2];   // current m-half, 4 frags x 2 ks
  bf16x8 b[4][2];   // all 4 n-frags of this kt

#define READ_A(mh, bufp) {                                                    \
    const char* Ab_ = (const char*)(bufp) + wm * 16384 + (mh) * 8192;         \
    _Pragma("unroll")                                                         \
    for (int mm = 0; mm < 4; ++mm) {                                          \
      const int r_ = (mm * 16 + lr) * 128;                                    \
      a[mm][0] = *(const bf16x8*)(Ab_ + r_ + soff0);                          \
      a[mm][1] = *(const bf16x8*)(Ab_ + r_ + soff1);                          \
    } }
#define READ_B(nh, bufp) {                                                    \
    const char* Bb_ = (const char*)(bufp) + 32768 + wn * 8192;                \
    _Pragma("unroll")                                                         \
    for (int nn = 0; nn < 2; ++nn) {                                          \
      const int r_ = (((nh) * 2 + nn) * 16 + lr) * 128;                       \
      b[(nh) * 2 + nn][0] = *(const bf16x8*)(Bb_ + r_ + soff0);               \
      b[(nh) * 2 + nn][1] = *(const bf16x8*)(Bb_ + r_ + soff1);               \
    } }
#define MFMA_QUAD(mh, nh)                                                     \
    __builtin_amdgcn_s_setprio(1);                                            \
    _Pragma("unroll")                                                         \
    for (int mm = 0; mm < 4; ++mm)                                            \
      _Pragma("unroll")                                                       \
      for (int nn = 0; nn < 2; ++nn) {                                        \
        MFMA16(acc[(mh) * 4 + mm][(nh) * 2 + nn], a[mm][0], b[(nh) * 2 + nn][0]); \
        MFMA16(acc[(mh) * 4 + mm][(nh) * 2 + nn], a[mm][1], b[(nh) * 2 + nn][1]); \
      }                                                                       \
    __builtin_amdgcn_s_setprio(0);

  // One K-tile body (R7-exact). nbuf reads ONLY at q3 (one barrier after all
  // waves' vmcnt(4) at q2 — the per-wave-vmcnt cross-wave RAW rule).
#define KT_BODY(buf, nbuf, kt, GUARDED)                                       \
  {                                                                           \
    /* q0: MFMA(m0,n01) ; stage A1(kt+1)->nbuf ; read b23 */                  \
    BAR();                                                                    \
    MFMA_QUAD(0, 0);                                                          \
    if (!(GUARDED) || (kt) + 1 < NT) STAGE_A1(nbuf, (kt) + 1);                \
    READ_B(1, buf);                                                           \
    /* q1: MFMA(m0,n23) ; stage B0(kt+2)->buf ; read a(m1) */                 \
    BAR();                                                                    \
    MFMA_QUAD(0, 1);                                                          \
    if (!(GUARDED) || (kt) + 2 < NT) STAGE_B0(buf, (kt) + 2);                 \
    READ_A(1, buf);                                                           \
    /* q2: MFMA(m1,n01) ; stage B1(kt+2)->buf ; vmcnt */                      \
    BAR();                                                                    \
    MFMA_QUAD(1, 0);                                                          \
    if (!(GUARDED) || (kt) + 2 < NT) {                                        \
      STAGE_B1(buf, (kt) + 2);                                                \
      asm volatile("s_waitcnt vmcnt(4)" ::: "memory");                        \
    } else {                                                                  \
      asm volatile("s_waitcnt vmcnt(0)" ::: "memory");                        \
    }                                                                         \
    /* q3: MFMA(m1,n23) ; stage A0(kt+2)->buf ; read next-kt a(m0),b(n0) */   \
    BAR();                                                                    \
    MFMA_QUAD(1, 1);                                                          \
    if (!(GUARDED) || (kt) + 2 < NT) STAGE_A0(buf, (kt) + 2);                 \
    if (!(GUARDED) || (kt) + 1 < NT) {                                        \
      READ_A(0, nbuf);                                                        \
      READ_B(0, nbuf);                                                        \
    }                                                                         \
  }

  // ---- prologue: stage buf0 fully + buf1 {A0,B0,B1}; A1(1) comes @q0(0) ----
  char* buf0 = lds;
  char* buf1 = lds + 65536;
  STAGE_A0(buf0, 0); STAGE_A1(buf0, 0); STAGE_B0(buf0, 0); STAGE_B1(buf0, 0);
  STAGE_A0(buf1, 1); STAGE_B0(buf1, 1); STAGE_B1(buf1, 1);
  asm volatile("s_waitcnt vmcnt(6)" ::: "memory");
  BAR();
  READ_A(0, buf0);
  READ_B(0, buf0);

  // ---- main: branchless pairs (kt = 0 .. NT-4) ----
  int kt = 0;
  for (; kt + 3 < NT; kt += 2) {
    KT_BODY(buf0, buf1, kt, 0);
    KT_BODY(buf1, buf0, kt + 1, 0);
  }
  // ---- tail: last 2 K-tiles, guarded ----
  for (; kt < NT; ++kt) {
    char* buf  = lds + ((kt & 1) << 16);
    char* nbuf = lds + (((kt & 1) ^ 1) << 16);
    KT_BODY(buf, nbuf, kt, 1);
  }

  // ---- epilogue: per-wave LDS transpose -> coalesced float4 C stores ----
  // Safe to reuse LDS: vmcnt(0) at NT-2/NT-1 q2 drained all gload_lds, and
  // every wave's ds_reads completed before the last q3 barrier. One BAR for
  // belt-and-braces; each wave then uses a PRIVATE 16KB slice (no cross-wave).
  BAR();
  {
    char* myl = lds + wave * 16384;      // 272B row stride: 64 f32 + 16B pad
    const int gcol = col0 + wn * 64 + lr * 4;
    const float4 bv4 = *(const float4*)&bias[gcol];
#pragma unroll
    for (int mp = 0; mp < 4; ++mp) {     // 32-row chunk = acc frags 2mp,2mp+1
#pragma unroll
      for (int mm = 0; mm < 2; ++mm)
#pragma unroll
        for (int n = 0; n < 4; ++n)
#pragma unroll
          for (int j = 0; j < 4; ++j)
            *(float*)(myl + (mm * 16 + hi * 4 + j) * 272 + (n * 16 + lr) * 4)
                = acc[mp * 2 + mm][n][j];
      // same-wave LDS RAW: compiler inserts lgkmcnt
#pragma unroll
      for (int r = 0; r < 8; ++r) {
        const int row = r * 4 + hi;      // 0..31
        float4 v = *(const float4*)(myl + row * 272 + lr * 16);
        v.x += bv4.x; v.y += bv4.y; v.z += bv4.z; v.w += bv4.w;
        const int grow = row0 + wm * 128 + mp * 32 + row;
        *(float4*)&C[(size_t)grow * N + gcol] = v;
      }
      // WAR before next chunk's writes: same-wave, compiler-ordered
    }
  }
#undef STAGE_A0
#undef STAGE_A1
#undef STAGE_B0
#undef STAGE_B1
#undef READ_A
#undef READ_B
#undef MFMA_QUAD
#undef KT_BODY
}

// ---------------------------------------------------------------------------
extern "C" void kernel_launch(void* const* d_in, const int* in_sizes, int n_in,
                              void* d_out, int out_size, void* d_ws, size_t ws_size,
                              hipStream_t stream) {
  const float* x      = (const float*)d_in[0];
  const int*   qw     = (const int*)d_in[1];
  const float* scales = (const float*)d_in[2];
  const float* zeros  = (const float*)d_in[3];
  const float* bias   = (const float*)d_in[4];
  float* out = (float*)d_out;

  const int OUT = in_sizes[4];                 // 4096
  const int IN  = in_sizes[1] / OUT;           // 4096
  const int M   = in_sizes[0] / IN;            // 8192

  unsigned short* wb = (unsigned short*)d_ws;                 // OUT*IN bf16
  unsigned short* xb = wb + (size_t)OUT * IN;                 // M*IN  bf16

  {
    int nw8 = OUT * IN / 8;                    // multiple of 256 -> no straddle
    int nx8 = (int)((size_t)M * IN / 8);
    int total = nw8 + nx8;
    prep_kernel<<<(total + 255) / 256, 256, 0, stream>>>(
        qw, scales, zeros, (ushort8*)wb, x, (ushort8*)xb, nw8, nx8);
  }
  {
    hipFuncSetAttribute((const void*)gemm256_kernel,
                        hipFuncAttributeMaxDynamicSharedMemorySize, 131072);
    dim3 grid((M / BM) * (OUT / BN));
    gemm256_kernel<<<grid, 512, 131072, stream>>>(xb, wb, bias, out, M, OUT, IN);
  }
}